// Round 9
// baseline (293.217 us; speedup 1.0000x reference)
//
#include <hip/hip_runtime.h>

#define NS 32768
#define NC 395
#define FD 512
#define S  8
#define CHUNK (NS / S)        // 4096 samples per split
#define TPB 256
#define NSLICE 32             // 16 floats (64 B) per slice
#define PAD 17                // padded LDS class row (17 coprime 32 -> bank spread)
#define NEL (NC * FD)

// Static device scratch — every slot rewritten each call.
// g_partial[(slice*2+mod)*S + split][class][16]   (~12.9 MB)
__device__ float g_partial[NSLICE * 2 * S * NC * 16];
__device__ int   g_pcount[S * NC];

// ---------------------------------------------------------------------------
// K1: one block per (slice, modality, split). Streams its 4096-sample window:
// each wave-inst reads 16 samples x 64 B fully-consumed cache lines (4 lanes x
// float4 per sample, stride 2 KB). Accumulates into a padded per-class LDS
// table via native ds_add_f32 (fire-and-forget). Zero global atomics; every
// input line read exactly once chip-wide.
__global__ __launch_bounds__(TPB)
void stream_sum_kernel(const float4* __restrict__ m1,
                       const float4* __restrict__ m2,
                       const int* __restrict__ targets,
                       float* __restrict__ out) {
    int b     = blockIdx.x;
    int split = b & (S - 1);
    int mod   = (b >> 3) & 1;
    int slice = b >> 4;
    int t     = threadIdx.x;

    if (b == 0 && t == 0) out[0] = 0.0f;   // zeroed before loss kernel

    __shared__ float acc[NC * PAD];   // 26.9 KB, bank-spread padded
    __shared__ int   stgt[CHUNK];     // 16 KB
    __shared__ int   lhist[NC];

    for (int i = t; i < NC * PAD; i += TPB) acc[i] = 0.0f;
    bool counting = (slice == 0 && mod == 0);
    if (counting)
        for (int i = t; i < NC; i += TPB) lhist[i] = 0;

    int base = split * CHUNK;
    const int4* t4 = reinterpret_cast<const int4*>(targets + base);
    for (int i = t; i < CHUNK / 4; i += TPB) {
        int4 v = t4[i];
        stgt[4 * i]     = v.x;
        stgt[4 * i + 1] = v.y;
        stgt[4 * i + 2] = v.z;
        stgt[4 * i + 3] = v.w;
    }
    __syncthreads();
    if (counting)
        for (int i = t; i < CHUNK; i += TPB) atomicAdd(&lhist[stgt[i]], 1);  // ds_add_u32

    const float4* src = mod ? m2 : m1;
    int g    = t >> 2;              // sample group within a 64-sample stripe
    int slot = t & 3;               // float4 slot within the 64 B window
    int col4 = slice * 4 + slot;    // float4 column within the 128-float4 row
    int so4  = slot * 4;            // float offset within the class row

    // 64 iterations, unrolled 4 -> 4 independent 64B-line loads in flight/thread.
    for (int it = 0; it < CHUNK / 64; it += 4) {
        int s0 = it * 64 + g;
        int s1 = s0 + 64, s2 = s0 + 128, s3 = s0 + 192;
        float4 v0 = src[(size_t)(base + s0) * 128 + col4];
        float4 v1 = src[(size_t)(base + s1) * 128 + col4];
        float4 v2 = src[(size_t)(base + s2) * 128 + col4];
        float4 v3 = src[(size_t)(base + s3) * 128 + col4];
        int c0 = stgt[s0], c1 = stgt[s1], c2 = stgt[s2], c3 = stgt[s3];
        float* a0 = &acc[c0 * PAD + so4];
        float* a1 = &acc[c1 * PAD + so4];
        float* a2 = &acc[c2 * PAD + so4];
        float* a3 = &acc[c3 * PAD + so4];
        atomicAdd(a0 + 0, v0.x); atomicAdd(a0 + 1, v0.y);
        atomicAdd(a0 + 2, v0.z); atomicAdd(a0 + 3, v0.w);
        atomicAdd(a1 + 0, v1.x); atomicAdd(a1 + 1, v1.y);
        atomicAdd(a1 + 2, v1.z); atomicAdd(a1 + 3, v1.w);
        atomicAdd(a2 + 0, v2.x); atomicAdd(a2 + 1, v2.y);
        atomicAdd(a2 + 2, v2.z); atomicAdd(a2 + 3, v2.w);
        atomicAdd(a3 + 0, v3.x); atomicAdd(a3 + 1, v3.y);
        atomicAdd(a3 + 2, v3.z); atomicAdd(a3 + 3, v3.w);
    }
    __syncthreads();

    // Epilogue: dump the (unpadded) per-class table to this block's slab.
    size_t sbase = (size_t)((slice * 2 + mod) * S + split) * NC * 16;
    float4* dst4 = reinterpret_cast<float4*>(g_partial + sbase);
    for (int i = t; i < NC * 4; i += TPB) {
        int c = i >> 2, qd = i & 3;
        const float* ap = &acc[c * PAD + qd * 4];
        dst4[i] = make_float4(ap[0], ap[1], ap[2], ap[3]);
    }
    if (counting)
        for (int i = t; i < NC; i += TPB) g_pcount[split * NC + i] = lhist[i];
}

// ---------------------------------------------------------------------------
__device__ __forceinline__ float smooth_l1(float d) {
    d = fabsf(d);
    return d < 1.0f ? 0.5f * d * d : d - 0.5f;
}

// K2: combine partials + counts, SmoothL1 weighted by count, two-level reduce.
__global__ void loss_kernel(const float* __restrict__ centers,
                            float* __restrict__ out) {
    __shared__ float scnt[NC];
    int t = threadIdx.x;   // 256
    for (int c = t; c < NC; c += 256) {
        int sc = 0;
        #pragma unroll
        for (int k = 0; k < S; k++) sc += g_pcount[k * NC + c];
        scnt[c] = (float)sc;
    }
    __syncthreads();

    float val = 0.0f;
    for (int gid = blockIdx.x * 256 + t; gid < NEL; gid += gridDim.x * 256) {
        int c = gid >> 9;              // FD == 512
        int d = gid & 511;
        int slice = d >> 4, dd = d & 15;
        float cnt = scnt[c];
        if (cnt > 0.0f) {
            float s1 = 0.0f, s2 = 0.0f;
            #pragma unroll
            for (int k = 0; k < S; k++) {
                s1 += g_partial[(size_t)((slice * 2 + 0) * S + k) * NC * 16 + c * 16 + dd];
                s2 += g_partial[(size_t)((slice * 2 + 1) * S + k) * NC * 16 + c * 16 + dd];
            }
            float ctr = centers[gid];
            float inv = 1.0f / cnt;
            val += cnt * (smooth_l1(s1 * inv - ctr) + smooth_l1(s2 * inv - ctr));
        }
    }

    for (int off = 32; off > 0; off >>= 1)
        val += __shfl_down(val, off, 64);
    __shared__ float wsum[4];
    int lane = t & 63, wid = t >> 6;
    if (lane == 0) wsum[wid] = val;
    __syncthreads();
    if (t == 0) {
        float sm = wsum[0] + wsum[1] + wsum[2] + wsum[3];
        atomicAdd(out, sm * 5.9604644775390625e-08f);  // 1/(N*D) = 2^-24
    }
}

extern "C" void kernel_launch(void* const* d_in, const int* in_sizes, int n_in,
                              void* d_out, int out_size, void* d_ws, size_t ws_size,
                              hipStream_t stream) {
    const float4* m1 = (const float4*)d_in[0];
    const float4* m2 = (const float4*)d_in[1];
    const float* centers = (const float*)d_in[2];
    const int* targets = (const int*)d_in[3];
    float* out = (float*)d_out;

    stream_sum_kernel<<<NSLICE * 2 * S, TPB, 0, stream>>>(m1, m2, targets, out);
    loss_kernel<<<512, 256, 0, stream>>>(centers, out);
}

// Round 10
// 291.741 us; speedup vs baseline: 1.0051x; 1.0051x over previous
//
#include <hip/hip_runtime.h>

#define NS 32768
#define NC 395
#define FD 512
#define S  8
#define CHUNK (NS / S)        // 4096 samples per split
#define TPB 256
#define NSLICE 32             // 16 floats (64 B) per slice
#define PAD 17                // padded LDS class row (17 coprime 32 -> bank spread)
#define NEL (NC * FD)

// Static device scratch — every slot rewritten each call.
// g_partial[(slice*2+mod)*S + split][class][16]   (~12.9 MB)
__device__ float g_partial[NSLICE * 2 * S * NC * 16];
__device__ int   g_pcount[S * NC];

// ---------------------------------------------------------------------------
// K1: one block per (slice, modality, split). Streams its 4096-sample window:
// each wave-inst reads 16 samples x 64 B fully-consumed cache lines (4 lanes x
// float4 per sample, stride 2 KB). Accumulates into a padded per-class LDS
// table via unsafeAtomicAdd -> native ds_add_f32, fire-and-forget (the R9
// version's atomicAdd compiled to a CAS loop: ~240 cyc dependent round-trip
// per lane-add = the entire 175 us). Zero global atomics.
__global__ __launch_bounds__(TPB)
void stream_sum_kernel(const float4* __restrict__ m1,
                       const float4* __restrict__ m2,
                       const int* __restrict__ targets,
                       float* __restrict__ out) {
    int b     = blockIdx.x;
    int split = b & (S - 1);
    int mod   = (b >> 3) & 1;
    int slice = b >> 4;
    int t     = threadIdx.x;

    if (b == 0 && t == 0) out[0] = 0.0f;   // zeroed before loss kernel

    __shared__ float acc[NC * PAD];   // 26.9 KB, bank-spread padded
    __shared__ int   stgt[CHUNK];     // 16 KB
    __shared__ int   lhist[NC];

    for (int i = t; i < NC * PAD; i += TPB) acc[i] = 0.0f;
    bool counting = (slice == 0 && mod == 0);
    if (counting)
        for (int i = t; i < NC; i += TPB) lhist[i] = 0;

    int base = split * CHUNK;
    const int4* t4 = reinterpret_cast<const int4*>(targets + base);
    for (int i = t; i < CHUNK / 4; i += TPB) {
        int4 v = t4[i];
        stgt[4 * i]     = v.x;
        stgt[4 * i + 1] = v.y;
        stgt[4 * i + 2] = v.z;
        stgt[4 * i + 3] = v.w;
    }
    __syncthreads();
    if (counting)
        for (int i = t; i < CHUNK; i += TPB) atomicAdd(&lhist[stgt[i]], 1);  // int: native ds_add_u32

    const float4* src = mod ? m2 : m1;
    int g    = t >> 2;              // sample group within a 64-sample stripe
    int slot = t & 3;               // float4 slot within the 64 B window
    int col4 = slice * 4 + slot;    // float4 column within the 128-float4 row
    int so4  = slot * 4;            // float offset within the class row

    // 64 iterations, unrolled 4 -> 4 independent 64B-line loads in flight/thread.
    for (int it = 0; it < CHUNK / 64; it += 4) {
        int s0 = it * 64 + g;
        int s1 = s0 + 64, s2 = s0 + 128, s3 = s0 + 192;
        float4 v0 = src[(size_t)(base + s0) * 128 + col4];
        float4 v1 = src[(size_t)(base + s1) * 128 + col4];
        float4 v2 = src[(size_t)(base + s2) * 128 + col4];
        float4 v3 = src[(size_t)(base + s3) * 128 + col4];
        int c0 = stgt[s0], c1 = stgt[s1], c2 = stgt[s2], c3 = stgt[s3];
        float* a0 = &acc[c0 * PAD + so4];
        float* a1 = &acc[c1 * PAD + so4];
        float* a2 = &acc[c2 * PAD + so4];
        float* a3 = &acc[c3 * PAD + so4];
        unsafeAtomicAdd(a0 + 0, v0.x); unsafeAtomicAdd(a0 + 1, v0.y);
        unsafeAtomicAdd(a0 + 2, v0.z); unsafeAtomicAdd(a0 + 3, v0.w);
        unsafeAtomicAdd(a1 + 0, v1.x); unsafeAtomicAdd(a1 + 1, v1.y);
        unsafeAtomicAdd(a1 + 2, v1.z); unsafeAtomicAdd(a1 + 3, v1.w);
        unsafeAtomicAdd(a2 + 0, v2.x); unsafeAtomicAdd(a2 + 1, v2.y);
        unsafeAtomicAdd(a2 + 2, v2.z); unsafeAtomicAdd(a2 + 3, v2.w);
        unsafeAtomicAdd(a3 + 0, v3.x); unsafeAtomicAdd(a3 + 1, v3.y);
        unsafeAtomicAdd(a3 + 2, v3.z); unsafeAtomicAdd(a3 + 3, v3.w);
    }
    __syncthreads();

    // Epilogue: dump the (unpadded) per-class table to this block's slab.
    size_t sbase = (size_t)((slice * 2 + mod) * S + split) * NC * 16;
    float4* dst4 = reinterpret_cast<float4*>(g_partial + sbase);
    for (int i = t; i < NC * 4; i += TPB) {
        int c = i >> 2, qd = i & 3;
        const float* ap = &acc[c * PAD + qd * 4];
        dst4[i] = make_float4(ap[0], ap[1], ap[2], ap[3]);
    }
    if (counting)
        for (int i = t; i < NC; i += TPB) g_pcount[split * NC + i] = lhist[i];
}

// ---------------------------------------------------------------------------
__device__ __forceinline__ float smooth_l1(float d) {
    d = fabsf(d);
    return d < 1.0f ? 0.5f * d * d : d - 0.5f;
}

// K2: combine partials + counts, SmoothL1 weighted by count, two-level reduce.
__global__ void loss_kernel(const float* __restrict__ centers,
                            float* __restrict__ out) {
    __shared__ float scnt[NC];
    int t = threadIdx.x;   // 256
    for (int c = t; c < NC; c += 256) {
        int sc = 0;
        #pragma unroll
        for (int k = 0; k < S; k++) sc += g_pcount[k * NC + c];
        scnt[c] = (float)sc;
    }
    __syncthreads();

    float val = 0.0f;
    for (int gid = blockIdx.x * 256 + t; gid < NEL; gid += gridDim.x * 256) {
        int c = gid >> 9;              // FD == 512
        int d = gid & 511;
        int slice = d >> 4, dd = d & 15;
        float cnt = scnt[c];
        if (cnt > 0.0f) {
            float s1 = 0.0f, s2 = 0.0f;
            #pragma unroll
            for (int k = 0; k < S; k++) {
                s1 += g_partial[(size_t)((slice * 2 + 0) * S + k) * NC * 16 + c * 16 + dd];
                s2 += g_partial[(size_t)((slice * 2 + 1) * S + k) * NC * 16 + c * 16 + dd];
            }
            float ctr = centers[gid];
            float inv = 1.0f / cnt;
            val += cnt * (smooth_l1(s1 * inv - ctr) + smooth_l1(s2 * inv - ctr));
        }
    }

    for (int off = 32; off > 0; off >>= 1)
        val += __shfl_down(val, off, 64);
    __shared__ float wsum[4];
    int lane = t & 63, wid = t >> 6;
    if (lane == 0) wsum[wid] = val;
    __syncthreads();
    if (t == 0) {
        float sm = wsum[0] + wsum[1] + wsum[2] + wsum[3];
        atomicAdd(out, sm * 5.9604644775390625e-08f);  // 1/(N*D) = 2^-24
    }
}

extern "C" void kernel_launch(void* const* d_in, const int* in_sizes, int n_in,
                              void* d_out, int out_size, void* d_ws, size_t ws_size,
                              hipStream_t stream) {
    const float4* m1 = (const float4*)d_in[0];
    const float4* m2 = (const float4*)d_in[1];
    const float* centers = (const float*)d_in[2];
    const int* targets = (const int*)d_in[3];
    float* out = (float*)d_out;

    stream_sum_kernel<<<NSLICE * 2 * S, TPB, 0, stream>>>(m1, m2, targets, out);
    loss_kernel<<<512, 256, 0, stream>>>(centers, out);
}

// Round 11
// 173.628 us; speedup vs baseline: 1.6888x; 1.6803x over previous
//
#include <hip/hip_runtime.h>

#define NS 32768
#define NC 395
#define FD 512
#define SPL 8
#define CHUNK (NS / SPL)   // 4096 targets scanned per block
#define TPB 256
#define NEL (NC * FD)

// Static device scratch — every slot rewritten each call.
// g_partial[((s*2+mod)*2+wsub)][class][512]   (~26 MB)
__device__ float g_partial[SPL * 2 * 2 * NC * FD];
__device__ int   g_pcount[SPL * NC];

// ---------------------------------------------------------------------------
__device__ __forceinline__ void f4add(float4& a, const float4 b) {
    a.x += b.x; a.y += b.y; a.z += b.z; a.w += b.w;
}

// K1: one block per (class, split). Scan: 4 hoisted int4 loads/thread, LDS
// compaction of CHUNK-LOCAL indices into ushort (8 KB — occupancy doubles vs
// R8's 20 KB). Gather: 4 waves = 2 per modality, even/odd rows; each lane
// covers a full 2 KB row (float4 at lane, lane+64), 4 rows unrolled -> 8
// coalesced 1KB wave-loads in flight per wave. Each wave writes its own
// partial slab (no LDS combine, no extra barrier).
__global__ __launch_bounds__(TPB)
void gather_sum_kernel(const float4* __restrict__ m1,
                       const float4* __restrict__ m2,
                       const int* __restrict__ targets,
                       float* __restrict__ out) {
    int c   = blockIdx.x >> 3;        // class
    int s   = blockIdx.x & (SPL - 1); // split
    int tid = threadIdx.x;

    if (blockIdx.x == 0 && tid == 0) out[0] = 0.0f;  // zero before loss kernel

    __shared__ unsigned short sidx[CHUNK];   // chunk-local indices, 8 KB
    __shared__ int scnt;

    // ---- scan phase: 4 int4 loads issued before the zeroing barrier ----
    int sbase = s * CHUNK;
    const int4* t4 = reinterpret_cast<const int4*>(targets + sbase);
    int4 ta = t4[tid];
    int4 tb = t4[tid + TPB];
    int4 tc = t4[tid + 2 * TPB];
    int4 td = t4[tid + 3 * TPB];
    if (tid == 0) scnt = 0;
    __syncthreads();
    int i0 = 4 * tid;                 // chunk-local
    int i1 = 4 * (tid + TPB);
    int i2 = 4 * (tid + 2 * TPB);
    int i3 = 4 * (tid + 3 * TPB);
    if (ta.x == c) sidx[atomicAdd(&scnt, 1)] = (unsigned short)i0;
    if (ta.y == c) sidx[atomicAdd(&scnt, 1)] = (unsigned short)(i0 + 1);
    if (ta.z == c) sidx[atomicAdd(&scnt, 1)] = (unsigned short)(i0 + 2);
    if (ta.w == c) sidx[atomicAdd(&scnt, 1)] = (unsigned short)(i0 + 3);
    if (tb.x == c) sidx[atomicAdd(&scnt, 1)] = (unsigned short)i1;
    if (tb.y == c) sidx[atomicAdd(&scnt, 1)] = (unsigned short)(i1 + 1);
    if (tb.z == c) sidx[atomicAdd(&scnt, 1)] = (unsigned short)(i1 + 2);
    if (tb.w == c) sidx[atomicAdd(&scnt, 1)] = (unsigned short)(i1 + 3);
    if (tc.x == c) sidx[atomicAdd(&scnt, 1)] = (unsigned short)i2;
    if (tc.y == c) sidx[atomicAdd(&scnt, 1)] = (unsigned short)(i2 + 1);
    if (tc.z == c) sidx[atomicAdd(&scnt, 1)] = (unsigned short)(i2 + 2);
    if (tc.w == c) sidx[atomicAdd(&scnt, 1)] = (unsigned short)(i2 + 3);
    if (td.x == c) sidx[atomicAdd(&scnt, 1)] = (unsigned short)i3;
    if (td.y == c) sidx[atomicAdd(&scnt, 1)] = (unsigned short)(i3 + 1);
    if (td.z == c) sidx[atomicAdd(&scnt, 1)] = (unsigned short)(i3 + 2);
    if (td.w == c) sidx[atomicAdd(&scnt, 1)] = (unsigned short)(i3 + 3);
    __syncthreads();
    int cnt = scnt;

    // ---- gather phase ----
    int wid  = tid >> 6;      // wave 0..3
    int mod  = wid >> 1;      // modality (wave-uniform)
    int wsub = wid & 1;       // even/odd row subset (wave-uniform)
    int lane = tid & 63;
    const float4* src = (mod ? m2 : m1) + (size_t)sbase * 128;

    float4 z = make_float4(0.f, 0.f, 0.f, 0.f);
    float4 aA0 = z, aB0 = z, aA1 = z, aB1 = z;

    int j = wsub;
    for (; j + 6 < cnt; j += 8) {      // 4 rows/iter (this wave's even/odd set)
        const float4* p0 = src + (size_t)sidx[j]     * 128;
        const float4* p1 = src + (size_t)sidx[j + 2] * 128;
        const float4* p2 = src + (size_t)sidx[j + 4] * 128;
        const float4* p3 = src + (size_t)sidx[j + 6] * 128;
        float4 vA0 = p0[lane], vB0 = p0[lane + 64];
        float4 vA1 = p1[lane], vB1 = p1[lane + 64];
        float4 vA2 = p2[lane], vB2 = p2[lane + 64];
        float4 vA3 = p3[lane], vB3 = p3[lane + 64];
        f4add(aA0, vA0); f4add(aB0, vB0);
        f4add(aA1, vA1); f4add(aB1, vB1);
        f4add(aA0, vA2); f4add(aB0, vB2);
        f4add(aA1, vA3); f4add(aB1, vB3);
    }
    for (; j < cnt; j += 2) {
        const float4* p = src + (size_t)sidx[j] * 128;
        f4add(aA0, p[lane]); f4add(aB0, p[lane + 64]);
    }
    f4add(aA0, aA1); f4add(aB0, aB1);

    // ---- per-wave partial slab (always written; zeros if no matches) ----
    float4* dst = reinterpret_cast<float4*>(g_partial);
    size_t base4 = (size_t)(((s * 2 + mod) * 2 + wsub) * NC + c) * 128;
    dst[base4 + lane]      = aA0;
    dst[base4 + lane + 64] = aB0;
    if (tid == 0) g_pcount[s * NC + c] = cnt;
}

// ---------------------------------------------------------------------------
__device__ __forceinline__ float smooth_l1(float d) {
    d = fabsf(d);
    return d < 1.0f ? 0.5f * d * d : d - 0.5f;
}

// K2: combine 32 partial slabs + counts, SmoothL1 weighted by count, reduce.
__global__ void loss_kernel(const float* __restrict__ centers,
                            float* __restrict__ out) {
    __shared__ float scnt[NC];
    int t = threadIdx.x;   // 256
    for (int c = t; c < NC; c += 256) {
        int sc = 0;
        #pragma unroll
        for (int k = 0; k < SPL; k++) sc += g_pcount[k * NC + c];
        scnt[c] = (float)sc;
    }
    __syncthreads();

    float val = 0.0f;
    for (int gid = blockIdx.x * 256 + t; gid < NEL; gid += gridDim.x * 256) {
        int c = gid >> 9;          // FD == 512
        float cnt = scnt[c];
        if (cnt > 0.0f) {
            float s1 = 0.0f, s2 = 0.0f;
            #pragma unroll
            for (int k = 0; k < SPL; k++) {
                s1 += g_partial[(size_t)((k * 2 + 0) * 2)     * NEL + gid];
                s1 += g_partial[(size_t)((k * 2 + 0) * 2 + 1) * NEL + gid];
                s2 += g_partial[(size_t)((k * 2 + 1) * 2)     * NEL + gid];
                s2 += g_partial[(size_t)((k * 2 + 1) * 2 + 1) * NEL + gid];
            }
            float ctr = centers[gid];
            float inv = 1.0f / cnt;
            val += cnt * (smooth_l1(s1 * inv - ctr) + smooth_l1(s2 * inv - ctr));
        }
    }

    for (int off = 32; off > 0; off >>= 1)
        val += __shfl_down(val, off, 64);
    __shared__ float wsum[4];
    int lane = t & 63, wid = t >> 6;
    if (lane == 0) wsum[wid] = val;
    __syncthreads();
    if (t == 0) {
        float sm = wsum[0] + wsum[1] + wsum[2] + wsum[3];
        atomicAdd(out, sm * 5.9604644775390625e-08f);  // 1/(N*D) = 2^-24
    }
}

extern "C" void kernel_launch(void* const* d_in, const int* in_sizes, int n_in,
                              void* d_out, int out_size, void* d_ws, size_t ws_size,
                              hipStream_t stream) {
    const float4* m1 = (const float4*)d_in[0];
    const float4* m2 = (const float4*)d_in[1];
    const float* centers = (const float*)d_in[2];
    const int* targets = (const int*)d_in[3];
    float* out = (float*)d_out;

    gather_sum_kernel<<<NC * SPL, TPB, 0, stream>>>(m1, m2, targets, out);
    loss_kernel<<<512, 256, 0, stream>>>(centers, out);
}